// Round 10
// baseline (547.091 us; speedup 1.0000x reference)
//
#include <hip/hip_runtime.h>
#include <hip/hip_bf16.h>

#define BATCH 512
#define TIN   256
#define TOUT  128
#define VOC   256
#define NZ    1024
#define EHID  64
#define DHID  128
#define SDIM  32

typedef __attribute__((ext_vector_type(8))) short bf16x8;
typedef __attribute__((ext_vector_type(4))) float f32x4;

__device__ __forceinline__ float bf2f(unsigned short u) {
  return __uint_as_float(((unsigned)u) << 16);
}
__device__ __forceinline__ unsigned short f2bf(float f) {
  unsigned u = __float_as_uint(f);
  u = u + 0x7FFFu + ((u >> 16) & 1u);
  return (unsigned short)(u >> 16);
}
__device__ __forceinline__ float sigf(float x) { return 1.0f / (1.0f + __expf(-x)); }
__device__ __forceinline__ float tanh_(float x) { return 1.0f - 2.0f / (1.0f + __expf(2.0f * x)); }

// lgkm-only block barrier (no vmcnt drain).
__device__ __forceinline__ void sync_lds() {
  asm volatile("s_waitcnt lgkmcnt(0)\n\ts_barrier" ::: "memory");
}

__device__ __forceinline__ bf16x8 pack8(float4 a, float4 b) {
  bf16x8 r;
  r[0] = (short)f2bf(a.x); r[1] = (short)f2bf(a.y);
  r[2] = (short)f2bf(a.z); r[3] = (short)f2bf(a.w);
  r[4] = (short)f2bf(b.x); r[5] = (short)f2bf(b.y);
  r[6] = (short)f2bf(b.z); r[7] = (short)f2bf(b.w);
  return r;
}

// ---------------------------------------------------------------------------
// findidx worker: one wave, one position (256 f32 one-hot row).
// ---------------------------------------------------------------------------
__device__ __forceinline__ void dev_findidx(const float* __restrict__ src,
                                            int pos, int lane,
                                            int* __restrict__ out) {
  float4 v = ((const float4*)src)[(size_t)pos * 64 + lane];
  int comp = v.x > 0.5f ? 0 : (v.y > 0.5f ? 1 : (v.z > 0.5f ? 2 : 3));
  bool hit = (v.x > 0.5f) || (v.y > 0.5f) || (v.z > 0.5f) || (v.w > 0.5f);
  int cand = hit ? lane * 4 + comp : (1 << 30);
#pragma unroll
  for (int off = 32; off > 0; off >>= 1) {
    int o = __shfl_xor(cand, off);
    cand = cand < o ? cand : o;
  }
  if (lane == 0) out[pos] = cand < VOC ? cand : VOC - 1;
}

// ---------------------------------------------------------------------------
// Launch A: WxT prep (0..63) | gx_const (64..191) | findidx enc (192..2239).
// ---------------------------------------------------------------------------
__global__ __launch_bounds__(256) void k_pre(
    const float* __restrict__ enc_Wih, const float* __restrict__ enc_b,
    const float* __restrict__ inp_onehot, const float* __restrict__ zia,
    float* __restrict__ WxT, float* __restrict__ gxc, int* __restrict__ enc_idx) {
  int blk = blockIdx.x, tid = threadIdx.x;
  if (blk < 64) {
    __shared__ float T[32][36];
    int r = tid >> 3, c = (tid & 7) * 4;
    int g0 = (blk >> 3) * 32, v0 = (blk & 7) * 32;
    float4 v = *(const float4*)(enc_Wih + (size_t)(g0 + r) * (VOC + NZ) + v0 + c);
    float bias = enc_b[g0 + r];
    T[c + 0][r] = v.x + bias; T[c + 1][r] = v.y + bias;
    T[c + 2][r] = v.z + bias; T[c + 3][r] = v.w + bias;
    __syncthreads();
    *(float4*)(WxT + (size_t)(v0 + r) * 256 + g0 + c) = *(const float4*)&T[r][c];
  } else if (blk < 192) {
    __shared__ float As[32][36], Bs[32][36];
    int q = blk - 64;
    int b0 = (q & 15) * 32, g0 = (q >> 4) * 32;
    int ldr = tid >> 3, ldc = (tid & 7) * 4;
    int tx = tid & 15, ty = tid >> 4;
    float a00 = 0.f, a01 = 0.f, a10 = 0.f, a11 = 0.f;
    for (int kc = 0; kc < NZ; kc += 32) {
      float4 av = *(const float4*)(zia + (size_t)(b0 + ldr) * NZ + kc + ldc);
      float4 bv = *(const float4*)(enc_Wih + (size_t)(g0 + ldr) * (VOC + NZ) + VOC + kc + ldc);
      __syncthreads();
      As[ldc + 0][ldr] = av.x; As[ldc + 1][ldr] = av.y;
      As[ldc + 2][ldr] = av.z; As[ldc + 3][ldr] = av.w;
      Bs[ldc + 0][ldr] = bv.x; Bs[ldc + 1][ldr] = bv.y;
      Bs[ldc + 2][ldr] = bv.z; Bs[ldc + 3][ldr] = bv.w;
      __syncthreads();
#pragma unroll
      for (int k = 0; k < 32; ++k) {
        float x0 = As[k][tx * 2], x1 = As[k][tx * 2 + 1];
        float y0 = Bs[k][ty * 2], y1 = Bs[k][ty * 2 + 1];
        a00 += x0 * y0; a01 += x0 * y1; a10 += x1 * y0; a11 += x1 * y1;
      }
    }
    float* o = gxc + (size_t)(b0 + tx * 2) * 256 + g0 + ty * 2;
    o[0] = a00; o[1] = a01; o[256] = a10; o[257] = a11;
  } else {
    int widx = (blk - 192) * 4 + (tid >> 6);  // 8192 waves
    int lane = tid & 63;
#pragma unroll 2
    for (int i = 0; i < 16; ++i)
      dev_findidx(inp_onehot, widx * 16 + i, lane, enc_idx);
  }
}

// ---------------------------------------------------------------------------
// Launch B: enc_scan (0..127) | WdecT prep (128..255) | WdT prep (256..287) |
// findidx dec (288..543).
// ---------------------------------------------------------------------------
#define ESTR 72
__global__ __launch_bounds__(256) void k_enc_fused(
    const float* __restrict__ enc_Whh, const float* __restrict__ WxT,
    const float* __restrict__ gxc, const int* __restrict__ enc_idx,
    float* __restrict__ h_enc,
    const float* __restrict__ dec_Wih, const float* __restrict__ dec_b,
    const float* __restrict__ out_W, const float* __restrict__ tgt,
    float* __restrict__ WdecT, float* __restrict__ WdT, int* __restrict__ dec_idx) {
  int blk = blockIdx.x, tid = threadIdx.x;
  if (blk < 128) {
    __shared__ unsigned short hA[2][16 * ESTR];
    __shared__ int idx_s[4][TIN];
    int b0 = blk * 4;
    int w = tid >> 6, lane = tid & 63, n = lane & 15, quad = lane >> 4;
    int j = w * 16 + n;
    // A-frag source row: rows != 0 mod 4 are never read from D, so all lanes
    // in a quad-group read the REAL row (n & 12) -> 4-lane LDS broadcast,
    // no bank conflicts, 4x less LDS traffic.
    int arow = n & 12;

    bf16x8 Bf[4][2];
#pragma unroll
    for (int ty = 0; ty < 4; ++ty)
#pragma unroll
      for (int kb = 0; kb < 2; ++kb) {
        const float* s = enc_Whh + (size_t)(ty * 64 + j) * EHID + kb * 32 + quad * 8;
        Bf[ty][kb] = pack8(*(const float4*)s, *(const float4*)(s + 4));
      }
    for (int i = tid; i < 16 * ESTR; i += 256) { hA[0][i] = 0; hA[1][i] = 0; }
    for (int i = tid; i < 4 * TIN; i += 256)
      idx_s[i >> 8][i & 255] = enc_idx[(size_t)(b0 + (i >> 8)) * TIN + (i & 255)];
    float gc[4];
#pragma unroll
    for (int ty = 0; ty < 4; ++ty) gc[ty] = gxc[(size_t)(b0 + quad) * 256 + ty * 64 + j];
    __syncthreads();

    float gx[4];
    {
      int id0 = idx_s[quad][0];
#pragma unroll
      for (int ty = 0; ty < 4; ++ty) gx[ty] = WxT[(size_t)id0 * 256 + ty * 64 + j];
    }
    // persistent accumulators: elements 1..3 carry bounded garbage (rows
    // 1..3 of D are never read); only element 0 is set precisely each step.
    f32x4 zz[4];
#pragma unroll
    for (int ty = 0; ty < 4; ++ty) zz[ty] = (f32x4)(0.f);
    float c0 = 0.0f, h = 0.0f;
    for (int t = 0; t < TIN; ++t) {
      const unsigned short* cur = hA[t & 1];
      bf16x8 a[2];
#pragma unroll
      for (int kb = 0; kb < 2; ++kb)
        a[kb] = *(const bf16x8*)(cur + arow * ESTR + kb * 32 + quad * 8);
      float gxn[4];
      int tn = (t + 1 < TIN) ? t + 1 : t;
      int idn = idx_s[quad][tn];
#pragma unroll
      for (int ty = 0; ty < 4; ++ty) gxn[ty] = WxT[(size_t)idn * 256 + ty * 64 + j];
#pragma unroll
      for (int ty = 0; ty < 4; ++ty) {
        f32x4 z = zz[ty];
        z[0] = gx[ty] + gc[ty];
        z = __builtin_amdgcn_mfma_f32_16x16x32_bf16(a[0], Bf[ty][0], z, 0, 0, 0);
        z = __builtin_amdgcn_mfma_f32_16x16x32_bf16(a[1], Bf[ty][1], z, 0, 0, 0);
        zz[ty] = z;
      }
      float gi = zz[0][0], gf = zz[1][0], gg = zz[2][0], go = zz[3][0];
      c0 = sigf(gf) * c0 + sigf(gi) * tanh_(gg);
      h = sigf(go) * tanh_(c0);
      hA[(t + 1) & 1][(quad * 4) * ESTR + j] = f2bf(h);
      gx[0] = gxn[0]; gx[1] = gxn[1]; gx[2] = gxn[2]; gx[3] = gxn[3];
      sync_lds();
    }
    h_enc[(size_t)(b0 + quad) * EHID + j] = h;
  } else if (blk < 256) {
    __shared__ float T[32][36];
    int q = blk - 128;
    int r = tid >> 3, c = (tid & 7) * 4;
    int g0 = (q >> 3) * 32, v0 = (q & 7) * 32;
    float4 v = *(const float4*)(dec_Wih + (size_t)(g0 + r) * VOC + v0 + c);
    float bias = dec_b[g0 + r];
    T[c + 0][r] = v.x + bias; T[c + 1][r] = v.y + bias;
    T[c + 2][r] = v.z + bias; T[c + 3][r] = v.w + bias;
    __syncthreads();
    *(float4*)(WdecT + (size_t)(v0 + r) * 512 + g0 + c) = *(const float4*)&T[r][c];
  } else if (blk < 288) {
    __shared__ float T2[32][36];
    int q = blk - 256;
    int r = tid >> 3, c = (tid & 7) * 4;
    int v0 = (q >> 2) * 32, k0 = (q & 3) * 32;
    float4 v = *(const float4*)(out_W + (size_t)(v0 + r) * (DHID + SDIM) + k0 + c);
    T2[c + 0][r] = v.x; T2[c + 1][r] = v.y; T2[c + 2][r] = v.z; T2[c + 3][r] = v.w;
    __syncthreads();
    *(float4*)(WdT + (size_t)(k0 + r) * 256 + v0 + c) = *(const float4*)&T2[r][c];
  } else {
    int widx = (blk - 288) * 4 + (tid >> 6);  // 4096 waves
    int lane = tid & 63;
#pragma unroll 2
    for (int i = 0; i < 16; ++i)
      dev_findidx(tgt, widx * 16 + i, lane, dec_idx);
  }
}

// ---------------------------------------------------------------------------
// Launch C: sg_fortza (0..511) | dh0 tiled GEMM (512..575).
// ---------------------------------------------------------------------------
__global__ __launch_bounds__(256) void k_mid(
    const float* __restrict__ h_enc, const float* __restrict__ fortza,
    const float* __restrict__ sg_W, const float* __restrict__ sg_b,
    const float* __restrict__ out_W, const float* __restrict__ out_b,
    const float* __restrict__ zia, const float* __restrict__ Wc_W,
    const float* __restrict__ Wc_b,
    float* __restrict__ out_fortza, float* __restrict__ fout,
    float* __restrict__ dh0) {
  int blk = blockIdx.x, tid = threadIdx.x;
  if (blk < 512) {
    __shared__ float hf[EHID], fz[SDIM], sg_s[2 * SDIM], fn[SDIM];
    int b = blk;
    if (tid < EHID) hf[tid] = h_enc[b * EHID + tid];
    if (tid >= EHID && tid < EHID + SDIM)
      fz[tid - EHID] = fortza[(size_t)b * SDIM + (tid - EHID)];
    __syncthreads();
    if (tid < 2 * SDIM) {
      float acc = sg_b[tid];
      const float* row = sg_W + (size_t)tid * (EHID + SDIM);
      for (int k = 0; k < EHID; ++k) acc += hf[k] * row[k];
      for (int jj = 0; jj < SDIM; ++jj) acc += fz[jj] * row[EHID + jj];
      sg_s[tid] = acc;
    }
    __syncthreads();
    if (tid < SDIM) {
      float gate = sigf(sg_s[tid]);
      float upd = tanh_(sg_s[SDIM + tid]);
      float v = gate * fz[tid] + (1.0f - gate) * upd;
      fn[tid] = v;
      out_fortza[(size_t)b * SDIM + tid] = v;
    }
    __syncthreads();
    {
      float acc = out_b[tid];
      const float* row = out_W + (size_t)tid * (DHID + SDIM) + DHID;
      for (int jj = 0; jj < SDIM; ++jj) acc += fn[jj] * row[jj];
      fout[b * VOC + tid] = acc;
    }
  } else {
    __shared__ float As[32][36], Bs[32][36];
    int q = blk - 512;
    int b0 = (q & 15) * 32, v0 = (q >> 4) * 32;
    int ldr = tid >> 3, ldc = (tid & 7) * 4;
    int tx = tid & 15, ty = tid >> 4;
    float a00 = 0.f, a01 = 0.f, a10 = 0.f, a11 = 0.f;
    for (int kc = 0; kc < EHID + NZ; kc += 32) {
      float4 av;
      if (kc < EHID)
        av = *(const float4*)(h_enc + (size_t)(b0 + ldr) * EHID + kc + ldc);
      else
        av = *(const float4*)(zia + (size_t)(b0 + ldr) * NZ + (kc - EHID) + ldc);
      float4 bv = *(const float4*)(Wc_W + (size_t)(v0 + ldr) * (EHID + NZ) + kc + ldc);
      __syncthreads();
      As[ldc + 0][ldr] = av.x; As[ldc + 1][ldr] = av.y;
      As[ldc + 2][ldr] = av.z; As[ldc + 3][ldr] = av.w;
      Bs[ldc + 0][ldr] = bv.x; Bs[ldc + 1][ldr] = bv.y;
      Bs[ldc + 2][ldr] = bv.z; Bs[ldc + 3][ldr] = bv.w;
      __syncthreads();
#pragma unroll
      for (int k = 0; k < 32; ++k) {
        float x0 = As[k][tx * 2], x1 = As[k][tx * 2 + 1];
        float y0 = Bs[k][ty * 2], y1 = Bs[k][ty * 2 + 1];
        a00 += x0 * y0; a01 += x0 * y1; a10 += x1 * y0; a11 += x1 * y1;
      }
    }
    float bb0 = Wc_b[v0 + ty * 2], bb1 = Wc_b[v0 + ty * 2 + 1];
    float* o = dh0 + (size_t)(b0 + tx * 2) * DHID + v0 + ty * 2;
    o[0] = tanh_(a00 + bb0); o[1] = tanh_(a01 + bb1);
    o[DHID] = tanh_(a10 + bb0); o[DHID + 1] = tanh_(a11 + bb1);
  }
}

// ---------------------------------------------------------------------------
// Launch D: decoder LSTM scan + fused logits. 128 blocks x 512 thr (8 waves).
// ---------------------------------------------------------------------------
#define DSTR 136
__global__ __launch_bounds__(512) void k_dec_logits(
    const float* __restrict__ dec_Whh, const float* __restrict__ WdecT,
    const int* __restrict__ dec_idx, const float* __restrict__ dh0,
    const float* __restrict__ WdT, const float* __restrict__ fout,
    float* __restrict__ out) {
  __shared__ unsigned short hA[2][16 * DSTR];
  __shared__ int idx_s[4][TOUT];
  int b0 = blockIdx.x * 4;
  int tid = threadIdx.x;
  int w = tid >> 6, lane = tid & 63, n = lane & 15, quad = lane >> 4;
  int j0 = w * 16, j = j0 + n;
  int arow = n & 12;  // LDS broadcast trick (see enc)

  bf16x8 Bf[4][4];
#pragma unroll
  for (int ty = 0; ty < 4; ++ty)
#pragma unroll
    for (int kb = 0; kb < 4; ++kb) {
      const float* src = dec_Whh + (size_t)(ty * 128 + j0 + n) * DHID + kb * 32 + quad * 8;
      Bf[ty][kb] = pack8(*(const float4*)src, *(const float4*)(src + 4));
    }
  bf16x8 BfL[2][4];
  float fo[2];
  float* op[2];
#pragma unroll
  for (int p = 0; p < 2; ++p) {
    int v = (w * 2 + p) * 16 + n;
#pragma unroll
    for (int kb = 0; kb < 4; ++kb) {
      const float* src = WdT + (size_t)(kb * 32 + quad * 8) * 256 + v;
      bf16x8 r;
#pragma unroll
      for (int i = 0; i < 8; ++i) r[i] = (short)f2bf(src[i * 256]);
      BfL[p][kb] = r;
    }
    fo[p] = fout[(size_t)(b0 + quad) * VOC + v];
    op[p] = out + (size_t)(b0 + quad) * TOUT * VOC + v;
  }
  for (int i = tid; i < 16 * DSTR; i += 512) {
    int m = i / DSTR, k = i - m * DSTR;
    float v = (k < DHID && (m & 3) == 0) ? dh0[(size_t)(b0 + (m >> 2)) * DHID + k] : 0.0f;
    hA[0][i] = f2bf(v);
    hA[1][i] = 0;
  }
  for (int i = tid; i < 4 * TOUT; i += 512)
    idx_s[i >> 7][i & 127] = dec_idx[(size_t)(b0 + (i >> 7)) * TOUT + (i & 127)];
  __syncthreads();

  float gx[4];
  {
    int id0 = idx_s[quad][0];
#pragma unroll
    for (int ty = 0; ty < 4; ++ty) gx[ty] = WdecT[(size_t)id0 * 512 + ty * 128 + j];
  }
  // persistent accumulators (elements 1..3 carry bounded garbage)
  f32x4 zz[4], zl[2];
#pragma unroll
  for (int ty = 0; ty < 4; ++ty) zz[ty] = (f32x4)(0.f);
  zl[0] = (f32x4)(0.f); zl[1] = (f32x4)(0.f);
  float c0 = 0.0f;
  for (int t = 0; t < TOUT; ++t) {
    const unsigned short* cur = hA[t & 1];
    bf16x8 a[4];
#pragma unroll
    for (int kb = 0; kb < 4; ++kb)
      a[kb] = *(const bf16x8*)(cur + arow * DSTR + kb * 32 + quad * 8);
    float gxn[4];
    int tn = (t + 1 < TOUT) ? t + 1 : t;
    int idn = idx_s[quad][tn];
#pragma unroll
    for (int ty = 0; ty < 4; ++ty) gxn[ty] = WdecT[(size_t)idn * 512 + ty * 128 + j];
    // scan MFMAs (critical path)
#pragma unroll
    for (int ty = 0; ty < 4; ++ty) {
      f32x4 z = zz[ty];
      z[0] = gx[ty];
#pragma unroll
      for (int kb = 0; kb < 4; ++kb)
        z = __builtin_amdgcn_mfma_f32_16x16x32_bf16(a[kb], Bf[ty][kb], z, 0, 0, 0);
      zz[ty] = z;
    }
    float gi = zz[0][0], gf = zz[1][0], gg = zz[2][0], go = zz[3][0];
    c0 = sigf(gf) * c0 + sigf(gi) * tanh_(gg);
    float h = sigf(go) * tanh_(c0);
    hA[(t + 1) & 1][(quad * 4) * DSTR + j] = f2bf(h);
    // fused logits for step t-1 (a[] = dhs[t-1])
    if (t > 0) {
#pragma unroll
      for (int p = 0; p < 2; ++p) {
        f32x4 z = zl[p];
        z[0] = fo[p];
#pragma unroll
        for (int kb = 0; kb < 4; ++kb)
          z = __builtin_amdgcn_mfma_f32_16x16x32_bf16(a[kb], BfL[p][kb], z, 0, 0, 0);
        zl[p] = z;
        *op[p] = z[0];
        op[p] += VOC;
      }
    }
    gx[0] = gxn[0]; gx[1] = gxn[1]; gx[2] = gxn[2]; gx[3] = gxn[3];
    sync_lds();
  }
  // epilogue: logits for t = TOUT-1 from h_TOUT (hA[0], TOUT even)
  {
    const unsigned short* cur = hA[0];
    bf16x8 a[4];
#pragma unroll
    for (int kb = 0; kb < 4; ++kb)
      a[kb] = *(const bf16x8*)(cur + arow * DSTR + kb * 32 + quad * 8);
#pragma unroll
    for (int p = 0; p < 2; ++p) {
      f32x4 z = zl[p];
      z[0] = fo[p];
#pragma unroll
      for (int kb = 0; kb < 4; ++kb)
        z = __builtin_amdgcn_mfma_f32_16x16x32_bf16(a[kb], BfL[p][kb], z, 0, 0, 0);
      *op[p] = z[0];
    }
  }
}

// ---------------------------------------------------------------------------
extern "C" void kernel_launch(void* const* d_in, const int* in_sizes, int n_in,
                              void* d_out, int out_size, void* d_ws, size_t ws_size,
                              hipStream_t stream) {
  const float* inp_onehot = (const float*)d_in[0];
  const float* zia     = (const float*)d_in[1];
  const float* tgt     = (const float*)d_in[2];
  const float* fortza  = (const float*)d_in[3];
  const float* enc_Wih = (const float*)d_in[4];
  const float* enc_Whh = (const float*)d_in[5];
  const float* enc_b   = (const float*)d_in[6];
  const float* sg_W    = (const float*)d_in[7];
  const float* sg_b    = (const float*)d_in[8];
  const float* Wc_W    = (const float*)d_in[9];
  const float* Wc_b    = (const float*)d_in[10];
  const float* dec_Wih = (const float*)d_in[11];
  const float* dec_Whh = (const float*)d_in[12];
  const float* dec_b   = (const float*)d_in[13];
  const float* out_W   = (const float*)d_in[14];
  const float* out_b   = (const float*)d_in[15];
  float* out = (float*)d_out;

  float* ws = (float*)d_ws;
  int* enc_idx  = (int*)d_ws;              // 131072 ints
  int* dec_idx  = enc_idx + BATCH * TIN;   //  65536 ints
  float* WxT    = ws + 196608;             //  65536 f
  float* WdecT  = ws + 262144;             // 131072 f
  float* WdT    = ws + 393216;             //  32768 f
  float* gxc    = ws + 425984;             // 131072 f
  float* h_enc  = ws + 557056;             //  32768 f
  float* dh0    = ws + 589824;             //  65536 f
  float* fout   = ws + 655360;             // 131072 f  (~3.1 MB total)

  k_pre<<<192 + 2048, 256, 0, stream>>>(
      enc_Wih, enc_b, inp_onehot, zia, WxT, gxc, enc_idx);
  k_enc_fused<<<288 + 1024, 256, 0, stream>>>(
      enc_Whh, WxT, gxc, enc_idx, h_enc,
      dec_Wih, dec_b, out_W, tgt, WdecT, WdT, dec_idx);
  k_mid<<<576, 256, 0, stream>>>(h_enc, fortza, sg_W, sg_b, out_W, out_b,
                                 zia, Wc_W, Wc_b,
                                 out + (size_t)BATCH * TOUT * VOC, fout, dh0);
  k_dec_logits<<<BATCH / 4, 512, 0, stream>>>(dec_Whh, WdecT, dec_idx, dh0,
                                              WdT, fout, out);
}